// Round 4
// baseline (4199.043 us; speedup 1.0000x reference)
//
#include <hip/hip_runtime.h>
#include <hip/hip_bf16.h>

#define TT 64
#define OT 64
#define ICH 16

__device__ __forceinline__ float  fma_t(float a, float b, float c)   { return fmaf(a, b, c); }
__device__ __forceinline__ double fma_t(double a, double b, double c){ return fma(a, b, c); }
__device__ __forceinline__ float fadd(float a, float b) { return __fadd_rn(a, b); }
__device__ __forceinline__ float fmul(float a, float b) { return __fmul_rn(a, b); }

// ---------------- transpose [B][R][C] -> [B][C][R] ----------------
__global__ __launch_bounds__(256) void transpose_kernel(const float* __restrict__ in,
                                                        float* __restrict__ out,
                                                        int R, int C) {
    __shared__ float tile[32][33];
    int b = blockIdx.z;
    int r0 = blockIdx.y * 32, c0 = blockIdx.x * 32;
    const float* ib = in + (size_t)b * R * C;
    float* ob = out + (size_t)b * R * C;
    int lx = threadIdx.x, ly = threadIdx.y;  // 32 x 8
#pragma unroll
    for (int i = 0; i < 32; i += 8) {
        tile[ly + i][lx] = ib[(size_t)(r0 + ly + i) * C + c0 + lx];
    }
    __syncthreads();
#pragma unroll
    for (int i = 0; i < 32; i += 8) {
        ob[(size_t)(c0 + ly + i) * R + r0 + lx] = tile[lx][ly + i];
    }
}

// ---------------- weight transposes ----------------
// conv:  w[O][I][K] -> wT[I][K][O]
__global__ __launch_bounds__(256) void wt_conv_kernel(const float* __restrict__ w,
                                                      float* __restrict__ wT,
                                                      int O, int I, int K) {
    int e = blockIdx.x * 256 + threadIdx.x;
    int total = O * I * K;
    if (e >= total) return;
    int k = e % K;
    int i = (e / K) % I;
    int o = e / (K * I);
    wT[((size_t)i * K + k) * O + o] = w[e];
}
// convT: w[I][O][K] -> wT[I][K][O]
__global__ __launch_bounds__(256) void wt_convT_kernel(const float* __restrict__ w,
                                                       float* __restrict__ wT,
                                                       int I, int O, int K) {
    int e = blockIdx.x * 256 + threadIdx.x;
    int total = O * I * K;
    if (e >= total) return;
    int k = e % K;
    int o = (e / K) % O;
    int i = e / (K * O);
    wT[((size_t)i * K + k) * O + o] = w[e];
}

// ---------------- generic conv1d (pad=1), ACC = float or double ----------------
template <int K, int STRIDE, bool RELU, typename ACC>
__global__ __launch_bounds__(256) void conv1d_kernel(const float* __restrict__ x,
                                                     const float* __restrict__ wT,
                                                     const float* __restrict__ bias,
                                                     float* __restrict__ y,
                                                     int I, int O, int Tin, int Tout) {
    const int b = blockIdx.z;
    const int o0 = blockIdx.y * OT;
    const int t0 = blockIdx.x * TT;
    const int tid = threadIdx.x;
    const int tx = tid & 15;   // t group
    const int ty = tid >> 4;   // o group
    constexpr int XW = (TT - 1) * STRIDE + K;
    __shared__ ACC xs[ICH][XW + 2];
    __shared__ ACC wl[ICH][K][OT];

    ACC acc[4][4];
#pragma unroll
    for (int j = 0; j < 4; j++)
#pragma unroll
        for (int c = 0; c < 4; c++) acc[j][c] = (ACC)0;

    const float* xb = x + (size_t)b * I * Tin;

    for (int ic0 = 0; ic0 < I; ic0 += ICH) {
        __syncthreads();
        for (int e = tid; e < ICH * XW; e += 256) {
            int ii = e / XW;
            int m = e - ii * XW;
            int tin = t0 * STRIDE - 1 + m;
            float v = 0.f;
            if (tin >= 0 && tin < Tin) v = xb[(size_t)(ic0 + ii) * Tin + tin];
            xs[ii][m] = (ACC)v;
        }
        for (int e = tid; e < ICH * K * OT; e += 256) {
            int q = e >> 6;
            (&wl[0][0][0])[e] = (ACC)wT[(size_t)(ic0 * K + q) * O + o0 + (e & 63)];
        }
        __syncthreads();
#pragma unroll
        for (int ii = 0; ii < ICH; ii++) {
            ACC xr[3 * STRIDE + K];
#pragma unroll
            for (int m = 0; m < 3 * STRIDE + K; m++)
                xr[m] = xs[ii][tx * 4 * STRIDE + m];
#pragma unroll
            for (int k = 0; k < K; k++) {
                ACC wv[4];
#pragma unroll
                for (int c = 0; c < 4; c++) wv[c] = wl[ii][k][ty * 4 + c];
#pragma unroll
                for (int j = 0; j < 4; j++) {
                    ACC xv = xr[j * STRIDE + k];
#pragma unroll
                    for (int c = 0; c < 4; c++) acc[j][c] = fma_t(xv, wv[c], acc[j][c]);
                }
            }
        }
    }
    float* yb = y + (size_t)b * O * Tout;
#pragma unroll
    for (int c = 0; c < 4; c++) {
        int o = o0 + ty * 4 + c;
        ACC bv = (ACC)bias[o];
        float4 v;
        ACC r0a = acc[0][c] + bv, r1 = acc[1][c] + bv, r2 = acc[2][c] + bv, r3 = acc[3][c] + bv;
        if (RELU) {
            r0a = r0a > (ACC)0 ? r0a : (ACC)0;
            r1  = r1  > (ACC)0 ? r1  : (ACC)0;
            r2  = r2  > (ACC)0 ? r2  : (ACC)0;
            r3  = r3  > (ACC)0 ? r3  : (ACC)0;
        }
        v.x = (float)r0a; v.y = (float)r1; v.z = (float)r2; v.w = (float)r3;
        *(float4*)&yb[(size_t)o * Tout + t0 + tx * 4] = v;
    }
}

// ---------------- ConvTranspose1d (K=4, stride=2, pad=1), fp32 ----------------
template <bool RELU>
__global__ __launch_bounds__(256) void convT_kernel(const float* __restrict__ x,
                                                    const float* __restrict__ wT,
                                                    const float* __restrict__ bias,
                                                    float* __restrict__ y,
                                                    int I, int O, int Tin) {
    const int Tout = 2 * Tin;
    const int b = blockIdx.z;
    const int o0 = blockIdx.y * OT;
    const int t0 = blockIdx.x * TT;
    const int tid = threadIdx.x;
    const int tx = tid & 15, ty = tid >> 4;
    constexpr int XW = 34;
    __shared__ float xs[ICH][XW + 2];
    __shared__ float wl[ICH][4][OT];
    float acc[4][4];
#pragma unroll
    for (int j = 0; j < 4; j++)
#pragma unroll
        for (int c = 0; c < 4; c++) acc[j][c] = 0.f;
    const float* xb = x + (size_t)b * I * Tin;
    for (int ic0 = 0; ic0 < I; ic0 += ICH) {
        __syncthreads();
        for (int e = tid; e < ICH * XW; e += 256) {
            int ii = e / XW, m = e - ii * XW;
            int tin = t0 / 2 - 1 + m;
            xs[ii][m] = (tin >= 0 && tin < Tin) ? xb[(size_t)(ic0 + ii) * Tin + tin] : 0.f;
        }
        for (int e = tid; e < ICH * 4 * OT; e += 256) {
            int q = e >> 6, oo = e & 63;
            (&wl[0][0][0])[e] = wT[(size_t)(ic0 * 4 + q) * O + o0 + oo];
        }
        __syncthreads();
#pragma unroll
        for (int ii = 0; ii < ICH; ii++) {
            float xr[4];
#pragma unroll
            for (int m = 0; m < 4; m++) xr[m] = xs[ii][2 * tx + m];
            float w0[4], w1[4], w2[4], w3[4];
#pragma unroll
            for (int c = 0; c < 4; c++) {
                w0[c] = wl[ii][0][ty * 4 + c];
                w1[c] = wl[ii][1][ty * 4 + c];
                w2[c] = wl[ii][2][ty * 4 + c];
                w3[c] = wl[ii][3][ty * 4 + c];
            }
#pragma unroll
            for (int c = 0; c < 4; c++) {
                acc[0][c] = fmaf(xr[1], w1[c], fmaf(xr[0], w3[c], acc[0][c]));
                acc[1][c] = fmaf(xr[2], w0[c], fmaf(xr[1], w2[c], acc[1][c]));
                acc[2][c] = fmaf(xr[2], w1[c], fmaf(xr[1], w3[c], acc[2][c]));
                acc[3][c] = fmaf(xr[3], w0[c], fmaf(xr[2], w2[c], acc[3][c]));
            }
        }
    }
    float* yb = y + (size_t)b * O * Tout;
#pragma unroll
    for (int c = 0; c < 4; c++) {
        int o = o0 + ty * 4 + c;
        float bv = bias[o];
        float4 v;
        v.x = acc[0][c] + bv;
        v.y = acc[1][c] + bv;
        v.z = acc[2][c] + bv;
        v.w = acc[3][c] + bv;
        if (RELU) {
            v.x = fmaxf(v.x, 0.f); v.y = fmaxf(v.y, 0.f);
            v.z = fmaxf(v.z, 0.f); v.w = fmaxf(v.w, 0.f);
        }
        *(float4*)&yb[(size_t)o * Tout + t0 + tx * 4] = v;
    }
}

// ---------------- numpy-style pairwise fp32 sum of squares (n=512) ----------------
// numpy pairwise_sum: n=512 -> (P128+P128) + (P128+P128); P128 = 8-accumulator
// unrolled loop, combine ((r0+r1)+(r2+r3))+((r4+r5)+(r6+r7)). All ops strict fp32.
template <typename GET>
__device__ __forceinline__ float np_sum512_sq(GET get) {
    float p[4];
#pragma unroll
    for (int blk = 0; blk < 4; blk++) {
        int base = blk * 128;
        float r[8];
#pragma unroll
        for (int j = 0; j < 8; j++) { float v = get(base + j); r[j] = fmul(v, v); }
        for (int i = 8; i < 128; i += 8) {
#pragma unroll
            for (int j = 0; j < 8; j++) { float v = get(base + i + j); r[j] = fadd(r[j], fmul(v, v)); }
        }
        p[blk] = fadd(fadd(fadd(r[0], r[1]), fadd(r[2], r[3])),
                      fadd(fadd(r[4], r[5]), fadd(r[6], r[7])));
    }
    return fadd(fadd(p[0], p[1]), fadd(p[2], p[3]));
}

// zn32[n] = fp32 pairwise sum of z_row^2 ; z layout [B][D][Tq]
__global__ __launch_bounds__(256) void zn32_kernel(const float* __restrict__ z, float* __restrict__ zn32) {
    int n = blockIdx.x * 256 + threadIdx.x;  // 8192
    int b = n >> 7, tq = n & 127;
    const float* zb = z + ((size_t)b << 16) + tq;
    zn32[n] = np_sum512_sq([&](int d) { return zb[d << 7]; });
}

// cn32[j] = fp32 pairwise sum of cb_row^2
__global__ __launch_bounds__(256) void cn32_kernel(const float* __restrict__ cb, float* __restrict__ cn32) {
    int j = blockIdx.x * 256 + threadIdx.x;  // 512
    const float* cr = cb + ((size_t)j << 9);
    cn32[j] = np_sum512_sq([&](int d) { return cr[d]; });
}

// ---------------- VQ argmin: exact fp64 dots + exact fp32 formula emulation ----------------
// Emulates numpy: d32 = fl32( fl32(zn32 + cn32_j) - 2*fl32(dot_j) ); argmin, ties -> lowest j.
__global__ __launch_bounds__(256) void vq_argmin_kernel(const float* __restrict__ z,
                                                        const float* __restrict__ cT,
                                                        const float* __restrict__ cn32,
                                                        const float* __restrict__ zn32,
                                                        int* __restrict__ idx_out,
                                                        float* __restrict__ idxf_out) {
    const int n0 = blockIdx.x * 64;
    const int b = n0 >> 7;
    const int tq0 = n0 & 127;
    const int tid = threadIdx.x;
    const int tx = tid & 15, ty = tid >> 4;
    constexpr int DCH = 32;
    __shared__ double zs[DCH][65];
    __shared__ double cs[DCH][64];
    __shared__ float rv[64][16];
    __shared__ int ri[64][16];

    float b1[4];
    int i1[4];
    float zn[4];
#pragma unroll
    for (int a = 0; a < 4; a++) {
        b1[a] = 3.4e38f; i1[a] = 0;
        zn[a] = zn32[n0 + ty * 4 + a];
    }

    for (int j0 = 0; j0 < 512; j0 += 64) {
        double acc[4][4];  // [n][j]
#pragma unroll
        for (int a = 0; a < 4; a++)
#pragma unroll
            for (int c = 0; c < 4; c++) acc[a][c] = 0.0;
        for (int d0 = 0; d0 < 512; d0 += DCH) {
            __syncthreads();
            for (int e = tid; e < DCH * 64; e += 256) {
                int dd = e >> 6, nn = e & 63;
                zs[dd][nn] = (double)z[((size_t)b * 512 + d0 + dd) * 128 + tq0 + nn];
            }
            for (int e = tid; e < DCH * 64; e += 256) {
                int dd = e >> 6, jj = e & 63;
                cs[dd][jj] = (double)cT[(size_t)(d0 + dd) * 512 + j0 + jj];
            }
            __syncthreads();
#pragma unroll
            for (int dd = 0; dd < DCH; dd++) {
                double zv[4], cv[4];
#pragma unroll
                for (int a = 0; a < 4; a++) zv[a] = zs[dd][ty * 4 + a];
#pragma unroll
                for (int c = 0; c < 4; c++) cv[c] = cs[dd][tx * 4 + c];
#pragma unroll
                for (int a = 0; a < 4; a++)
#pragma unroll
                    for (int c = 0; c < 4; c++) acc[a][c] = fma(zv[a], cv[c], acc[a][c]);
            }
        }
#pragma unroll
        for (int c = 0; c < 4; c++) {
            int j = j0 + tx * 4 + c;
            float cnv = cn32[j];
#pragma unroll
            for (int a = 0; a < 4; a++) {
                float C32 = (float)acc[a][c];          // sgemm entry ~ correctly rounded
                float t1  = fadd(zn[a], cnv);          // fl32(zn + cn)
                float d32 = fadd(t1, fmul(-2.f, C32)); // fl32(t1 - 2*C)
                if (d32 < b1[a]) { b1[a] = d32; i1[a] = j; }  // ties keep earlier j
            }
        }
    }
    __syncthreads();
#pragma unroll
    for (int a = 0; a < 4; a++) {
        rv[ty * 4 + a][tx] = b1[a];
        ri[ty * 4 + a][tx] = i1[a];
    }
    __syncthreads();
    if (tid < 64) {
        float bv = rv[tid][0];
        int bi = ri[tid][0];
#pragma unroll
        for (int t = 1; t < 16; t++) {
            float v = rv[tid][t];
            int ji = ri[tid][t];
            if (v < bv || (v == bv && ji < bi)) { bv = v; bi = ji; }
        }
        idx_out[n0 + tid] = bi;
        idxf_out[n0 + tid] = (float)bi;
    }
}

// ---------------- straight-through + commitment loss ----------------
__global__ __launch_bounds__(256) void zq_st_kernel(const float* __restrict__ z,
                                                    const float* __restrict__ cb,
                                                    const int* __restrict__ idx,
                                                    float* __restrict__ zq,
                                                    double* __restrict__ lossAcc) {
    const int total = 64 * 512 * 128;
    double part = 0.0;
    for (int e = blockIdx.x * 256 + threadIdx.x; e < total; e += gridDim.x * 256) {
        int tq = e & 127;
        int d = (e >> 7) & 511;
        int b = e >> 16;
        float zv = z[e];
        float cv = cb[(size_t)idx[(b << 7) + tq] * 512 + d];
        double diff = (double)zv - (double)cv;
        part = fma(diff, diff, part);
        zq[e] = zv + (cv - zv);
    }
    __shared__ double red[256];
    red[threadIdx.x] = part;
    __syncthreads();
    for (int s = 128; s; s >>= 1) {
        if (threadIdx.x < (unsigned)s) red[threadIdx.x] += red[threadIdx.x + s];
        __syncthreads();
    }
    if (threadIdx.x == 0) atomicAdd(lossAcc, red[0]);
}

__global__ void finalize_kernel(const double* __restrict__ lossAcc, float* __restrict__ out_loss) {
    *out_loss = (float)(0.25 * (*lossAcc) / (double)(64 * 512 * 128));
}

// ---------------- host ----------------
extern "C" void kernel_launch(void* const* d_in, const int* in_sizes, int n_in,
                              void* d_out, int out_size, void* d_ws, size_t ws_size,
                              hipStream_t stream) {
    const float* x    = (const float*)d_in[0];
    const float* ew1  = (const float*)d_in[1];  const float* eb1 = (const float*)d_in[2];
    const float* ew2  = (const float*)d_in[3];  const float* eb2 = (const float*)d_in[4];
    const float* ew3  = (const float*)d_in[5];  const float* eb3 = (const float*)d_in[6];
    const float* ew4  = (const float*)d_in[7];  const float* eb4 = (const float*)d_in[8];
    const float* ew5  = (const float*)d_in[9];  const float* eb5 = (const float*)d_in[10];
    const float* cb   = (const float*)d_in[11];
    const float* dw1  = (const float*)d_in[12]; const float* db1  = (const float*)d_in[13];
    const float* dwt2 = (const float*)d_in[14]; const float* dbt2 = (const float*)d_in[15];
    const float* dw3  = (const float*)d_in[16]; const float* db3  = (const float*)d_in[17];
    const float* dwt4 = (const float*)d_in[18]; const float* dbt4 = (const float*)d_in[19];
    const float* dw5  = (const float*)d_in[20]; const float* db5  = (const float*)d_in[21];

    float* out = (float*)d_out;
    float* ws = (float*)d_ws;

    const int B = 64, T = 512, F = 256, D = 512, Kcb = 512, Tq = 128;

    size_t off = 0;
    auto alloc = [&](size_t n) { size_t o = off; off += n; return o; };
    float* bufA = ws + alloc((size_t)B * 512 * 512);
    float* bufB = ws + alloc((size_t)B * 512 * 512);
    float* bufC = ws + alloc((size_t)B * 512 * 512);
    float* cT    = ws + alloc((size_t)D * Kcb);
    float* cn32  = ws + alloc(Kcb);
    float* zn32  = ws + alloc(B * Tq);
    int*   idxb  = (int*)(ws + alloc(B * Tq));
    double* lossAcc = (double*)(ws + alloc(2));
    float* wtE1  = ws + alloc((size_t)256 * 3 * 256);
    float* wtE2  = ws + alloc((size_t)256 * 4 * 256);
    float* wtE3  = ws + alloc((size_t)256 * 3 * 512);
    float* wtE4  = ws + alloc((size_t)512 * 4 * 512);
    float* wtE5  = ws + alloc((size_t)512 * 3 * 512);
    float* wtD1  = ws + alloc((size_t)512 * 3 * 512);
    float* wtDT2 = ws + alloc((size_t)512 * 4 * 512);
    float* wtD3  = ws + alloc((size_t)512 * 3 * 256);
    float* wtDT4 = ws + alloc((size_t)256 * 4 * 256);
    float* wtD5  = ws + alloc((size_t)256 * 3 * 256);
    (void)ws_size; (void)in_sizes; (void)n_in; (void)out_size;

    hipMemsetAsync(lossAcc, 0, sizeof(double), stream);

    auto wtc = [&](const float* w, float* wT, int O, int I, int K) {
        int tot = O * I * K;
        wt_conv_kernel<<<(tot + 255) / 256, 256, 0, stream>>>(w, wT, O, I, K);
    };
    auto wtct = [&](const float* w, float* wT, int I, int O, int K) {
        int tot = O * I * K;
        wt_convT_kernel<<<(tot + 255) / 256, 256, 0, stream>>>(w, wT, I, O, K);
    };
    wtc(ew1, wtE1, 256, 256, 3);
    wtc(ew2, wtE2, 256, 256, 4);
    wtc(ew3, wtE3, 512, 256, 3);
    wtc(ew4, wtE4, 512, 512, 4);
    wtc(ew5, wtE5, 512, 512, 3);
    wtc(dw1, wtD1, 512, 512, 3);
    wtct(dwt2, wtDT2, 512, 512, 4);
    wtc(dw3, wtD3, 256, 512, 3);
    wtct(dwt4, wtDT4, 256, 256, 4);
    wtc(dw5, wtD5, 256, 256, 3);

    // codebook prep
    transpose_kernel<<<dim3(512 / 32, 512 / 32, 1), dim3(32, 8), 0, stream>>>(cb, cT, Kcb, D);
    cn32_kernel<<<2, 256, 0, stream>>>(cb, cn32);

    // x [B,T,F] -> bufA [B,F,T]
    transpose_kernel<<<dim3(F / 32, T / 32, B), dim3(32, 8), 0, stream>>>(x, bufA, T, F);

    // encoder (fp64 accumulation)
    conv1d_kernel<3, 1, true,  double><<<dim3(512 / TT, 256 / OT, B), 256, 0, stream>>>(bufA, wtE1, eb1, bufB, 256, 256, 512, 512);
    conv1d_kernel<4, 2, true,  double><<<dim3(256 / TT, 256 / OT, B), 256, 0, stream>>>(bufB, wtE2, eb2, bufC, 256, 256, 512, 256);
    conv1d_kernel<3, 1, true,  double><<<dim3(256 / TT, 512 / OT, B), 256, 0, stream>>>(bufC, wtE3, eb3, bufA, 256, 512, 256, 256);
    conv1d_kernel<4, 2, true,  double><<<dim3(128 / TT, 512 / OT, B), 256, 0, stream>>>(bufA, wtE4, eb4, bufB, 512, 512, 256, 128);
    conv1d_kernel<3, 1, false, double><<<dim3(128 / TT, 512 / OT, B), 256, 0, stream>>>(bufB, wtE5, eb5, bufC, 512, 512, 128, 128);

    // VQ: fp32-formula-faithful argmin
    zn32_kernel<<<32, 256, 0, stream>>>(bufC, zn32);
    vq_argmin_kernel<<<128, 256, 0, stream>>>(bufC, cT, cn32, zn32, idxb, out + (size_t)8388608);
    zq_st_kernel<<<2048, 256, 0, stream>>>(bufC, cb, idxb, bufA, lossAcc);

    // decoder (fp32)
    conv1d_kernel<3, 1, true,  float><<<dim3(128 / TT, 512 / OT, B), 256, 0, stream>>>(bufA, wtD1, db1, bufB, 512, 512, 128, 128);
    convT_kernel<true><<<dim3(256 / TT, 512 / OT, B), 256, 0, stream>>>(bufB, wtDT2, dbt2, bufA, 512, 512, 128);
    conv1d_kernel<3, 1, true,  float><<<dim3(256 / TT, 256 / OT, B), 256, 0, stream>>>(bufA, wtD3, db3, bufB, 512, 256, 256, 256);
    convT_kernel<true><<<dim3(512 / TT, 256 / OT, B), 256, 0, stream>>>(bufB, wtDT4, dbt4, bufA, 256, 256, 256);
    conv1d_kernel<3, 1, false, float><<<dim3(512 / TT, 256 / OT, B), 256, 0, stream>>>(bufA, wtD5, db5, bufB, 256, 256, 512, 512);

    transpose_kernel<<<dim3(T / 32, F / 32, B), dim3(32, 8), 0, stream>>>(bufB, out, F, T);

    finalize_kernel<<<1, 1, 0, stream>>>(lossAcc, out + (size_t)8396800);
}

// Round 5
// 3627.158 us; speedup vs baseline: 1.1577x; 1.1577x over previous
//
#include <hip/hip_runtime.h>
#include <hip/hip_bf16.h>

#define TT 64
#define OT 64
#define ICH 16

__device__ __forceinline__ float fadd(float a, float b) { return __fadd_rn(a, b); }
__device__ __forceinline__ float fmul(float a, float b) { return __fmul_rn(a, b); }

// ---------------- transpose [B][R][C] -> [B][C][R] ----------------
__global__ __launch_bounds__(256) void transpose_kernel(const float* __restrict__ in,
                                                        float* __restrict__ out,
                                                        int R, int C) {
    __shared__ float tile[32][33];
    int b = blockIdx.z;
    int r0 = blockIdx.y * 32, c0 = blockIdx.x * 32;
    const float* ib = in + (size_t)b * R * C;
    float* ob = out + (size_t)b * R * C;
    int lx = threadIdx.x, ly = threadIdx.y;  // 32 x 8
#pragma unroll
    for (int i = 0; i < 32; i += 8) {
        tile[ly + i][lx] = ib[(size_t)(r0 + ly + i) * C + c0 + lx];
    }
    __syncthreads();
#pragma unroll
    for (int i = 0; i < 32; i += 8) {
        ob[(size_t)(c0 + ly + i) * R + r0 + lx] = tile[lx][ly + i];
    }
}

// ---------------- weight transposes ----------------
// conv:  w[O][I][K] -> wT[I][K][O]
__global__ __launch_bounds__(256) void wt_conv_kernel(const float* __restrict__ w,
                                                      float* __restrict__ wT,
                                                      int O, int I, int K) {
    int e = blockIdx.x * 256 + threadIdx.x;
    int total = O * I * K;
    if (e >= total) return;
    int k = e % K;
    int i = (e / K) % I;
    int o = e / (K * I);
    wT[((size_t)i * K + k) * O + o] = w[e];
}
// convT: w[I][O][K] -> wT[I][K][O]
__global__ __launch_bounds__(256) void wt_convT_kernel(const float* __restrict__ w,
                                                       float* __restrict__ wT,
                                                       int I, int O, int K) {
    int e = blockIdx.x * 256 + threadIdx.x;
    int total = O * I * K;
    if (e >= total) return;
    int k = e % K;
    int o = (e / K) % O;
    int i = e / (K * O);
    wT[((size_t)i * K + k) * O + o] = w[e];
}

// ---------------- encoder conv1d: fp32 LDS, fp64 accumulate ----------------
// x: [B][I][Tin], wT: [I][K][O], y: [B][O][Tout]; pad=1.
// STRIDE==1: generic K. STRIDE==2: K must be 4; x staged as even/odd phase
// arrays so fragment reads are 16B lane-stride (bank-conflict-free).
template <int K, int STRIDE, bool RELU>
__global__ __launch_bounds__(256) void conv1d_f64_kernel(const float* __restrict__ x,
                                                         const float* __restrict__ wT,
                                                         const float* __restrict__ bias,
                                                         float* __restrict__ y,
                                                         int I, int O, int Tin, int Tout) {
    const int b = blockIdx.z;
    const int o0 = blockIdx.y * OT;
    const int t0 = blockIdx.x * TT;
    const int tid = threadIdx.x;
    const int tx = tid & 15;   // t group
    const int ty = tid >> 4;   // o group

    double acc[4][4];  // [t][o]
#pragma unroll
    for (int j = 0; j < 4; j++)
#pragma unroll
        for (int c = 0; c < 4; c++) acc[j][c] = 0.0;

    const float* xb = x + (size_t)b * I * Tin;

    if constexpr (STRIDE == 1) {
        constexpr int XW = TT + K - 1;  // 66
        __shared__ float xs[ICH][XW + 2];
        __shared__ float wl[ICH][K][OT];
        for (int ic0 = 0; ic0 < I; ic0 += ICH) {
            __syncthreads();
            for (int e = tid; e < ICH * XW; e += 256) {
                int ii = e / XW, m = e - ii * XW;
                int tin = t0 - 1 + m;
                xs[ii][m] = (tin >= 0 && tin < Tin) ? xb[(size_t)(ic0 + ii) * Tin + tin] : 0.f;
            }
            for (int e = tid; e < ICH * K * OT; e += 256) {
                int q = e >> 6;
                (&wl[0][0][0])[e] = wT[(size_t)(ic0 * K + q) * O + o0 + (e & 63)];
            }
            __syncthreads();
#pragma unroll
            for (int ii = 0; ii < ICH; ii++) {
                double xr[4 + K - 1];
#pragma unroll
                for (int m = 0; m < 4 + K - 1; m++) xr[m] = (double)xs[ii][tx * 4 + m];
#pragma unroll
                for (int k = 0; k < K; k++) {
                    double wv[4];
#pragma unroll
                    for (int c = 0; c < 4; c++) wv[c] = (double)wl[ii][k][ty * 4 + c];
#pragma unroll
                    for (int j = 0; j < 4; j++)
#pragma unroll
                        for (int c = 0; c < 4; c++) acc[j][c] = fma(xr[j + k], wv[c], acc[j][c]);
                }
            }
        }
    } else {
        static_assert(STRIDE == 2 && K == 4, "stride-2 path is K=4 only");
        constexpr int XP = TT + 1;  // 65 per phase
        __shared__ float xs_e[ICH][XP + 3];
        __shared__ float xs_o[ICH][XP + 3];
        __shared__ float wl[ICH][4][OT];
        for (int ic0 = 0; ic0 < I; ic0 += ICH) {
            __syncthreads();
            for (int e = tid; e < ICH * XP; e += 256) {
                int ii = e / XP, s = e - ii * XP;
                const float* xrow = xb + (size_t)(ic0 + ii) * Tin;
                int te = 2 * (t0 + s);      // even sample
                int to = te - 1;            // odd sample
                xs_e[ii][s] = (te < Tin) ? xrow[te] : 0.f;
                xs_o[ii][s] = (to >= 0) ? xrow[to] : 0.f;
            }
            for (int e = tid; e < ICH * 4 * OT; e += 256) {
                int q = e >> 6;
                (&wl[0][0][0])[e] = wT[(size_t)(ic0 * 4 + q) * O + o0 + (e & 63)];
            }
            __syncthreads();
#pragma unroll
            for (int ii = 0; ii < ICH; ii++) {
                // y[t] = o[t]*w0 + e[t]*w1 + o[t+1]*w2 + e[t+1]*w3  (t rel. block)
                double re[5], ro[5];
#pragma unroll
                for (int m = 0; m < 5; m++) {
                    re[m] = (double)xs_e[ii][tx * 4 + m];
                    ro[m] = (double)xs_o[ii][tx * 4 + m];
                }
#pragma unroll
                for (int k = 0; k < 4; k++) {
                    double wv[4];
#pragma unroll
                    for (int c = 0; c < 4; c++) wv[c] = (double)wl[ii][k][ty * 4 + c];
                    const double* xr = (k & 1) ? re : ro;
                    const int offs = k >> 1;
#pragma unroll
                    for (int j = 0; j < 4; j++)
#pragma unroll
                        for (int c = 0; c < 4; c++) acc[j][c] = fma(xr[j + offs], wv[c], acc[j][c]);
                }
            }
        }
    }

    float* yb = y + (size_t)b * O * Tout;
#pragma unroll
    for (int c = 0; c < 4; c++) {
        int o = o0 + ty * 4 + c;
        double bv = (double)bias[o];
        double r0 = acc[0][c] + bv, r1 = acc[1][c] + bv, r2 = acc[2][c] + bv, r3 = acc[3][c] + bv;
        if (RELU) {
            r0 = r0 > 0.0 ? r0 : 0.0;
            r1 = r1 > 0.0 ? r1 : 0.0;
            r2 = r2 > 0.0 ? r2 : 0.0;
            r3 = r3 > 0.0 ? r3 : 0.0;
        }
        float4 v;
        v.x = (float)r0; v.y = (float)r1; v.z = (float)r2; v.w = (float)r3;
        *(float4*)&yb[(size_t)o * Tout + t0 + tx * 4] = v;
    }
}

// ---------------- decoder conv1d (pad=1), fp32 ----------------
template <int K, int STRIDE, bool RELU>
__global__ __launch_bounds__(256) void conv1d_kernel(const float* __restrict__ x,
                                                     const float* __restrict__ wT,
                                                     const float* __restrict__ bias,
                                                     float* __restrict__ y,
                                                     int I, int O, int Tin, int Tout) {
    const int b = blockIdx.z;
    const int o0 = blockIdx.y * OT;
    const int t0 = blockIdx.x * TT;
    const int tid = threadIdx.x;
    const int tx = tid & 15;
    const int ty = tid >> 4;
    constexpr int XW = (TT - 1) * STRIDE + K;
    __shared__ float xs[ICH][XW + 2];
    __shared__ float wl[ICH][K][OT];

    float acc[4][4];
#pragma unroll
    for (int j = 0; j < 4; j++)
#pragma unroll
        for (int c = 0; c < 4; c++) acc[j][c] = 0.f;

    const float* xb = x + (size_t)b * I * Tin;

    for (int ic0 = 0; ic0 < I; ic0 += ICH) {
        __syncthreads();
        for (int e = tid; e < ICH * XW; e += 256) {
            int ii = e / XW;
            int m = e - ii * XW;
            int tin = t0 * STRIDE - 1 + m;
            float v = 0.f;
            if (tin >= 0 && tin < Tin) v = xb[(size_t)(ic0 + ii) * Tin + tin];
            xs[ii][m] = v;
        }
        for (int e = tid; e < ICH * K * OT; e += 256) {
            int q = e >> 6;
            (&wl[0][0][0])[e] = wT[(size_t)(ic0 * K + q) * O + o0 + (e & 63)];
        }
        __syncthreads();
#pragma unroll
        for (int ii = 0; ii < ICH; ii++) {
            float xr[3 * STRIDE + K];
#pragma unroll
            for (int m = 0; m < 3 * STRIDE + K; m++)
                xr[m] = xs[ii][tx * 4 * STRIDE + m];
#pragma unroll
            for (int k = 0; k < K; k++) {
                float wv[4];
#pragma unroll
                for (int c = 0; c < 4; c++) wv[c] = wl[ii][k][ty * 4 + c];
#pragma unroll
                for (int j = 0; j < 4; j++) {
                    float xv = xr[j * STRIDE + k];
#pragma unroll
                    for (int c = 0; c < 4; c++) acc[j][c] = fmaf(xv, wv[c], acc[j][c]);
                }
            }
        }
    }
    float* yb = y + (size_t)b * O * Tout;
#pragma unroll
    for (int c = 0; c < 4; c++) {
        int o = o0 + ty * 4 + c;
        float bv = bias[o];
        float4 v;
        v.x = acc[0][c] + bv;
        v.y = acc[1][c] + bv;
        v.z = acc[2][c] + bv;
        v.w = acc[3][c] + bv;
        if (RELU) {
            v.x = fmaxf(v.x, 0.f); v.y = fmaxf(v.y, 0.f);
            v.z = fmaxf(v.z, 0.f); v.w = fmaxf(v.w, 0.f);
        }
        *(float4*)&yb[(size_t)o * Tout + t0 + tx * 4] = v;
    }
}

// ---------------- ConvTranspose1d (K=4, stride=2, pad=1), fp32 ----------------
template <bool RELU>
__global__ __launch_bounds__(256) void convT_kernel(const float* __restrict__ x,
                                                    const float* __restrict__ wT,
                                                    const float* __restrict__ bias,
                                                    float* __restrict__ y,
                                                    int I, int O, int Tin) {
    const int Tout = 2 * Tin;
    const int b = blockIdx.z;
    const int o0 = blockIdx.y * OT;
    const int t0 = blockIdx.x * TT;
    const int tid = threadIdx.x;
    const int tx = tid & 15, ty = tid >> 4;
    constexpr int XW = 34;
    __shared__ float xs[ICH][XW + 2];
    __shared__ float wl[ICH][4][OT];
    float acc[4][4];
#pragma unroll
    for (int j = 0; j < 4; j++)
#pragma unroll
        for (int c = 0; c < 4; c++) acc[j][c] = 0.f;
    const float* xb = x + (size_t)b * I * Tin;
    for (int ic0 = 0; ic0 < I; ic0 += ICH) {
        __syncthreads();
        for (int e = tid; e < ICH * XW; e += 256) {
            int ii = e / XW, m = e - ii * XW;
            int tin = t0 / 2 - 1 + m;
            xs[ii][m] = (tin >= 0 && tin < Tin) ? xb[(size_t)(ic0 + ii) * Tin + tin] : 0.f;
        }
        for (int e = tid; e < ICH * 4 * OT; e += 256) {
            int q = e >> 6, oo = e & 63;
            (&wl[0][0][0])[e] = wT[(size_t)(ic0 * 4 + q) * O + o0 + oo];
        }
        __syncthreads();
#pragma unroll
        for (int ii = 0; ii < ICH; ii++) {
            float xr[4];
#pragma unroll
            for (int m = 0; m < 4; m++) xr[m] = xs[ii][2 * tx + m];
            float w0[4], w1[4], w2[4], w3[4];
#pragma unroll
            for (int c = 0; c < 4; c++) {
                w0[c] = wl[ii][0][ty * 4 + c];
                w1[c] = wl[ii][1][ty * 4 + c];
                w2[c] = wl[ii][2][ty * 4 + c];
                w3[c] = wl[ii][3][ty * 4 + c];
            }
#pragma unroll
            for (int c = 0; c < 4; c++) {
                acc[0][c] = fmaf(xr[1], w1[c], fmaf(xr[0], w3[c], acc[0][c]));
                acc[1][c] = fmaf(xr[2], w0[c], fmaf(xr[1], w2[c], acc[1][c]));
                acc[2][c] = fmaf(xr[2], w1[c], fmaf(xr[1], w3[c], acc[2][c]));
                acc[3][c] = fmaf(xr[3], w0[c], fmaf(xr[2], w2[c], acc[3][c]));
            }
        }
    }
    float* yb = y + (size_t)b * O * Tout;
#pragma unroll
    for (int c = 0; c < 4; c++) {
        int o = o0 + ty * 4 + c;
        float bv = bias[o];
        float4 v;
        v.x = acc[0][c] + bv;
        v.y = acc[1][c] + bv;
        v.z = acc[2][c] + bv;
        v.w = acc[3][c] + bv;
        if (RELU) {
            v.x = fmaxf(v.x, 0.f); v.y = fmaxf(v.y, 0.f);
            v.z = fmaxf(v.z, 0.f); v.w = fmaxf(v.w, 0.f);
        }
        *(float4*)&yb[(size_t)o * Tout + t0 + tx * 4] = v;
    }
}

// ---------------- numpy-style pairwise fp32 sum of squares (n=512) ----------------
template <typename GET>
__device__ __forceinline__ float np_sum512_sq(GET get) {
    float p[4];
#pragma unroll
    for (int blk = 0; blk < 4; blk++) {
        int base = blk * 128;
        float r[8];
#pragma unroll
        for (int j = 0; j < 8; j++) { float v = get(base + j); r[j] = fmul(v, v); }
        for (int i = 8; i < 128; i += 8) {
#pragma unroll
            for (int j = 0; j < 8; j++) { float v = get(base + i + j); r[j] = fadd(r[j], fmul(v, v)); }
        }
        p[blk] = fadd(fadd(fadd(r[0], r[1]), fadd(r[2], r[3])),
                      fadd(fadd(r[4], r[5]), fadd(r[6], r[7])));
    }
    return fadd(fadd(p[0], p[1]), fadd(p[2], p[3]));
}

// zn32[n] = fp32 pairwise sum of z_row^2 ; z layout [B][D][Tq]
__global__ __launch_bounds__(256) void zn32_kernel(const float* __restrict__ z, float* __restrict__ zn32) {
    int n = blockIdx.x * 256 + threadIdx.x;  // 8192
    int b = n >> 7, tq = n & 127;
    const float* zb = z + ((size_t)b << 16) + tq;
    zn32[n] = np_sum512_sq([&](int d) { return zb[d << 7]; });
}

// cn32[j] = fp32 pairwise sum of cb_row^2
__global__ __launch_bounds__(256) void cn32_kernel(const float* __restrict__ cb, float* __restrict__ cn32) {
    int j = blockIdx.x * 256 + threadIdx.x;  // 512
    const float* cr = cb + ((size_t)j << 9);
    cn32[j] = np_sum512_sq([&](int d) { return cr[d]; });
}

// ---------------- VQ argmin: exact fp64 dots + exact fp32 formula emulation ----------------
__global__ __launch_bounds__(256) void vq_argmin_kernel(const float* __restrict__ z,
                                                        const float* __restrict__ cT,
                                                        const float* __restrict__ cn32,
                                                        const float* __restrict__ zn32,
                                                        int* __restrict__ idx_out,
                                                        float* __restrict__ idxf_out) {
    const int n0 = blockIdx.x * 64;
    const int b = n0 >> 7;
    const int tq0 = n0 & 127;
    const int tid = threadIdx.x;
    const int tx = tid & 15, ty = tid >> 4;
    constexpr int DCH = 32;
    __shared__ double zs[DCH][65];
    __shared__ double cs[DCH][64];
    __shared__ float rv[64][16];
    __shared__ int ri[64][16];

    float b1[4];
    int i1[4];
    float zn[4];
#pragma unroll
    for (int a = 0; a < 4; a++) {
        b1[a] = 3.4e38f; i1[a] = 0;
        zn[a] = zn32[n0 + ty * 4 + a];
    }

    for (int j0 = 0; j0 < 512; j0 += 64) {
        double acc[4][4];
#pragma unroll
        for (int a = 0; a < 4; a++)
#pragma unroll
            for (int c = 0; c < 4; c++) acc[a][c] = 0.0;
        for (int d0 = 0; d0 < 512; d0 += DCH) {
            __syncthreads();
            for (int e = tid; e < DCH * 64; e += 256) {
                int dd = e >> 6, nn = e & 63;
                zs[dd][nn] = (double)z[((size_t)b * 512 + d0 + dd) * 128 + tq0 + nn];
            }
            for (int e = tid; e < DCH * 64; e += 256) {
                int dd = e >> 6, jj = e & 63;
                cs[dd][jj] = (double)cT[(size_t)(d0 + dd) * 512 + j0 + jj];
            }
            __syncthreads();
#pragma unroll
            for (int dd = 0; dd < DCH; dd++) {
                double zv[4], cv[4];
#pragma unroll
                for (int a = 0; a < 4; a++) zv[a] = zs[dd][ty * 4 + a];
#pragma unroll
                for (int c = 0; c < 4; c++) cv[c] = cs[dd][tx * 4 + c];
#pragma unroll
                for (int a = 0; a < 4; a++)
#pragma unroll
                    for (int c = 0; c < 4; c++) acc[a][c] = fma(zv[a], cv[c], acc[a][c]);
            }
        }
#pragma unroll
        for (int c = 0; c < 4; c++) {
            int j = j0 + tx * 4 + c;
            float cnv = cn32[j];
#pragma unroll
            for (int a = 0; a < 4; a++) {
                float C32 = (float)acc[a][c];
                float t1  = fadd(zn[a], cnv);
                float d32 = fadd(t1, fmul(-2.f, C32));
                if (d32 < b1[a]) { b1[a] = d32; i1[a] = j; }
            }
        }
    }
    __syncthreads();
#pragma unroll
    for (int a = 0; a < 4; a++) {
        rv[ty * 4 + a][tx] = b1[a];
        ri[ty * 4 + a][tx] = i1[a];
    }
    __syncthreads();
    if (tid < 64) {
        float bv = rv[tid][0];
        int bi = ri[tid][0];
#pragma unroll
        for (int t = 1; t < 16; t++) {
            float v = rv[tid][t];
            int ji = ri[tid][t];
            if (v < bv || (v == bv && ji < bi)) { bv = v; bi = ji; }
        }
        idx_out[n0 + tid] = bi;
        idxf_out[n0 + tid] = (float)bi;
    }
}

// ---------------- straight-through + commitment loss ----------------
__global__ __launch_bounds__(256) void zq_st_kernel(const float* __restrict__ z,
                                                    const float* __restrict__ cb,
                                                    const int* __restrict__ idx,
                                                    float* __restrict__ zq,
                                                    double* __restrict__ lossAcc) {
    const int total = 64 * 512 * 128;
    double part = 0.0;
    for (int e = blockIdx.x * 256 + threadIdx.x; e < total; e += gridDim.x * 256) {
        int tq = e & 127;
        int d = (e >> 7) & 511;
        int b = e >> 16;
        float zv = z[e];
        float cv = cb[(size_t)idx[(b << 7) + tq] * 512 + d];
        double diff = (double)zv - (double)cv;
        part = fma(diff, diff, part);
        zq[e] = zv + (cv - zv);
    }
    __shared__ double red[256];
    red[threadIdx.x] = part;
    __syncthreads();
    for (int s = 128; s; s >>= 1) {
        if (threadIdx.x < (unsigned)s) red[threadIdx.x] += red[threadIdx.x + s];
        __syncthreads();
    }
    if (threadIdx.x == 0) atomicAdd(lossAcc, red[0]);
}

__global__ void finalize_kernel(const double* __restrict__ lossAcc, float* __restrict__ out_loss) {
    *out_loss = (float)(0.25 * (*lossAcc) / (double)(64 * 512 * 128));
}

// ---------------- host ----------------
extern "C" void kernel_launch(void* const* d_in, const int* in_sizes, int n_in,
                              void* d_out, int out_size, void* d_ws, size_t ws_size,
                              hipStream_t stream) {
    const float* x    = (const float*)d_in[0];
    const float* ew1  = (const float*)d_in[1];  const float* eb1 = (const float*)d_in[2];
    const float* ew2  = (const float*)d_in[3];  const float* eb2 = (const float*)d_in[4];
    const float* ew3  = (const float*)d_in[5];  const float* eb3 = (const float*)d_in[6];
    const float* ew4  = (const float*)d_in[7];  const float* eb4 = (const float*)d_in[8];
    const float* ew5  = (const float*)d_in[9];  const float* eb5 = (const float*)d_in[10];
    const float* cb   = (const float*)d_in[11];
    const float* dw1  = (const float*)d_in[12]; const float* db1  = (const float*)d_in[13];
    const float* dwt2 = (const float*)d_in[14]; const float* dbt2 = (const float*)d_in[15];
    const float* dw3  = (const float*)d_in[16]; const float* db3  = (const float*)d_in[17];
    const float* dwt4 = (const float*)d_in[18]; const float* dbt4 = (const float*)d_in[19];
    const float* dw5  = (const float*)d_in[20]; const float* db5  = (const float*)d_in[21];

    float* out = (float*)d_out;
    float* ws = (float*)d_ws;

    const int B = 64, T = 512, F = 256, D = 512, Kcb = 512, Tq = 128;

    size_t off = 0;
    auto alloc = [&](size_t n) { size_t o = off; off += n; return o; };
    float* bufA = ws + alloc((size_t)B * 512 * 512);
    float* bufB = ws + alloc((size_t)B * 512 * 512);
    float* bufC = ws + alloc((size_t)B * 512 * 512);
    float* cT    = ws + alloc((size_t)D * Kcb);
    float* cn32  = ws + alloc(Kcb);
    float* zn32  = ws + alloc(B * Tq);
    int*   idxb  = (int*)(ws + alloc(B * Tq));
    double* lossAcc = (double*)(ws + alloc(2));
    float* wtE1  = ws + alloc((size_t)256 * 3 * 256);
    float* wtE2  = ws + alloc((size_t)256 * 4 * 256);
    float* wtE3  = ws + alloc((size_t)256 * 3 * 512);
    float* wtE4  = ws + alloc((size_t)512 * 4 * 512);
    float* wtE5  = ws + alloc((size_t)512 * 3 * 512);
    float* wtD1  = ws + alloc((size_t)512 * 3 * 512);
    float* wtDT2 = ws + alloc((size_t)512 * 4 * 512);
    float* wtD3  = ws + alloc((size_t)512 * 3 * 256);
    float* wtDT4 = ws + alloc((size_t)256 * 4 * 256);
    float* wtD5  = ws + alloc((size_t)256 * 3 * 256);
    (void)ws_size; (void)in_sizes; (void)n_in; (void)out_size;

    hipMemsetAsync(lossAcc, 0, sizeof(double), stream);

    auto wtc = [&](const float* w, float* wT, int O, int I, int K) {
        int tot = O * I * K;
        wt_conv_kernel<<<(tot + 255) / 256, 256, 0, stream>>>(w, wT, O, I, K);
    };
    auto wtct = [&](const float* w, float* wT, int I, int O, int K) {
        int tot = O * I * K;
        wt_convT_kernel<<<(tot + 255) / 256, 256, 0, stream>>>(w, wT, I, O, K);
    };
    wtc(ew1, wtE1, 256, 256, 3);
    wtc(ew2, wtE2, 256, 256, 4);
    wtc(ew3, wtE3, 512, 256, 3);
    wtc(ew4, wtE4, 512, 512, 4);
    wtc(ew5, wtE5, 512, 512, 3);
    wtc(dw1, wtD1, 512, 512, 3);
    wtct(dwt2, wtDT2, 512, 512, 4);
    wtc(dw3, wtD3, 256, 512, 3);
    wtct(dwt4, wtDT4, 256, 256, 4);
    wtc(dw5, wtD5, 256, 256, 3);

    // codebook prep
    transpose_kernel<<<dim3(512 / 32, 512 / 32, 1), dim3(32, 8), 0, stream>>>(cb, cT, Kcb, D);
    cn32_kernel<<<2, 256, 0, stream>>>(cb, cn32);

    // x [B,T,F] -> bufA [B,F,T]
    transpose_kernel<<<dim3(F / 32, T / 32, B), dim3(32, 8), 0, stream>>>(x, bufA, T, F);

    // encoder (fp64 accumulation, fp32 LDS)
    conv1d_f64_kernel<3, 1, true ><<<dim3(512 / TT, 256 / OT, B), 256, 0, stream>>>(bufA, wtE1, eb1, bufB, 256, 256, 512, 512);
    conv1d_f64_kernel<4, 2, true ><<<dim3(256 / TT, 256 / OT, B), 256, 0, stream>>>(bufB, wtE2, eb2, bufC, 256, 256, 512, 256);
    conv1d_f64_kernel<3, 1, true ><<<dim3(256 / TT, 512 / OT, B), 256, 0, stream>>>(bufC, wtE3, eb3, bufA, 256, 512, 256, 256);
    conv1d_f64_kernel<4, 2, true ><<<dim3(128 / TT, 512 / OT, B), 256, 0, stream>>>(bufA, wtE4, eb4, bufB, 512, 512, 256, 128);
    conv1d_f64_kernel<3, 1, false><<<dim3(128 / TT, 512 / OT, B), 256, 0, stream>>>(bufB, wtE5, eb5, bufC, 512, 512, 128, 128);

    // VQ: fp32-formula-faithful argmin
    zn32_kernel<<<32, 256, 0, stream>>>(bufC, zn32);
    vq_argmin_kernel<<<128, 256, 0, stream>>>(bufC, cT, cn32, zn32, idxb, out + (size_t)8388608);
    zq_st_kernel<<<2048, 256, 0, stream>>>(bufC, cb, idxb, bufA, lossAcc);

    // decoder (fp32)
    conv1d_kernel<3, 1, true ><<<dim3(128 / TT, 512 / OT, B), 256, 0, stream>>>(bufA, wtD1, db1, bufB, 512, 512, 128, 128);
    convT_kernel<true><<<dim3(256 / TT, 512 / OT, B), 256, 0, stream>>>(bufB, wtDT2, dbt2, bufA, 512, 512, 128);
    conv1d_kernel<3, 1, true ><<<dim3(256 / TT, 256 / OT, B), 256, 0, stream>>>(bufA, wtD3, db3, bufB, 512, 256, 256, 256);
    convT_kernel<true><<<dim3(512 / TT, 256 / OT, B), 256, 0, stream>>>(bufB, wtDT4, dbt4, bufA, 256, 256, 256);
    conv1d_kernel<3, 1, false><<<dim3(512 / TT, 256 / OT, B), 256, 0, stream>>>(bufA, wtD5, db5, bufB, 256, 256, 512, 512);

    transpose_kernel<<<dim3(T / 32, F / 32, B), dim3(32, 8), 0, stream>>>(bufB, out, F, T);

    finalize_kernel<<<1, 1, 0, stream>>>(lossAcc, out + (size_t)8396800);
}

// Round 7
// 3184.035 us; speedup vs baseline: 1.3188x; 1.1392x over previous
//
#include <hip/hip_runtime.h>
#include <hip/hip_bf16.h>

#define TT 64
#define OT 64
#define ICH 16

__device__ __forceinline__ float fadd(float a, float b) { return __fadd_rn(a, b); }
__device__ __forceinline__ float fmul(float a, float b) { return __fmul_rn(a, b); }

// ---------------- transpose [B][R][C] -> [B][C][R] ----------------
__global__ __launch_bounds__(256) void transpose_kernel(const float* __restrict__ in,
                                                        float* __restrict__ out,
                                                        int R, int C) {
    __shared__ float tile[32][33];
    int b = blockIdx.z;
    int r0 = blockIdx.y * 32, c0 = blockIdx.x * 32;
    const float* ib = in + (size_t)b * R * C;
    float* ob = out + (size_t)b * R * C;
    int lx = threadIdx.x, ly = threadIdx.y;  // 32 x 8
#pragma unroll
    for (int i = 0; i < 32; i += 8) {
        tile[ly + i][lx] = ib[(size_t)(r0 + ly + i) * C + c0 + lx];
    }
    __syncthreads();
#pragma unroll
    for (int i = 0; i < 32; i += 8) {
        ob[(size_t)(c0 + ly + i) * R + r0 + lx] = tile[lx][ly + i];
    }
}

// ---------------- weight transposes ----------------
// conv:  w[O][I][K] -> wT[I][K][O]
__global__ __launch_bounds__(256) void wt_conv_kernel(const float* __restrict__ w,
                                                      float* __restrict__ wT,
                                                      int O, int I, int K) {
    int e = blockIdx.x * 256 + threadIdx.x;
    int total = O * I * K;
    if (e >= total) return;
    int k = e % K;
    int i = (e / K) % I;
    int o = e / (K * I);
    wT[((size_t)i * K + k) * O + o] = w[e];
}
// convT: w[I][O][K] -> wT[I][K][O]
__global__ __launch_bounds__(256) void wt_convT_kernel(const float* __restrict__ w,
                                                       float* __restrict__ wT,
                                                       int I, int O, int K) {
    int e = blockIdx.x * 256 + threadIdx.x;
    int total = O * I * K;
    if (e >= total) return;
    int k = e % K;
    int o = (e / K) % O;
    int i = e / (K * O);
    wT[((size_t)i * K + k) * O + o] = w[e];
}

// ---------------- encoder conv1d: fp32 LDS, fp64 accumulate ----------------
template <int K, int STRIDE, bool RELU>
__global__ __launch_bounds__(256) void conv1d_f64_kernel(const float* __restrict__ x,
                                                         const float* __restrict__ wT,
                                                         const float* __restrict__ bias,
                                                         float* __restrict__ y,
                                                         int I, int O, int Tin, int Tout) {
    const int b = blockIdx.z;
    const int o0 = blockIdx.y * OT;
    const int t0 = blockIdx.x * TT;
    const int tid = threadIdx.x;
    const int tx = tid & 15;   // t group
    const int ty = tid >> 4;   // o group

    double acc[4][4];  // [t][o]
#pragma unroll
    for (int j = 0; j < 4; j++)
#pragma unroll
        for (int c = 0; c < 4; c++) acc[j][c] = 0.0;

    const float* xb = x + (size_t)b * I * Tin;

    if constexpr (STRIDE == 1) {
        constexpr int XW = TT + K - 1;  // 66
        __shared__ float xs[ICH][XW + 2];
        __shared__ float wl[ICH][K][OT];
        for (int ic0 = 0; ic0 < I; ic0 += ICH) {
            __syncthreads();
            for (int e = tid; e < ICH * XW; e += 256) {
                int ii = e / XW, m = e - ii * XW;
                int tin = t0 - 1 + m;
                xs[ii][m] = (tin >= 0 && tin < Tin) ? xb[(size_t)(ic0 + ii) * Tin + tin] : 0.f;
            }
            for (int e = tid; e < ICH * K * OT; e += 256) {
                int q = e >> 6;
                (&wl[0][0][0])[e] = wT[(size_t)(ic0 * K + q) * O + o0 + (e & 63)];
            }
            __syncthreads();
#pragma unroll
            for (int ii = 0; ii < ICH; ii++) {
                double xr[4 + K - 1];
#pragma unroll
                for (int m = 0; m < 4 + K - 1; m++) xr[m] = (double)xs[ii][tx * 4 + m];
#pragma unroll
                for (int k = 0; k < K; k++) {
                    double wv[4];
#pragma unroll
                    for (int c = 0; c < 4; c++) wv[c] = (double)wl[ii][k][ty * 4 + c];
#pragma unroll
                    for (int j = 0; j < 4; j++)
#pragma unroll
                        for (int c = 0; c < 4; c++) acc[j][c] = fma(xr[j + k], wv[c], acc[j][c]);
                }
            }
        }
    } else {
        static_assert(STRIDE == 2 && K == 4, "stride-2 path is K=4 only");
        constexpr int XP = TT + 1;  // 65 per phase
        __shared__ float xs_e[ICH][XP + 3];
        __shared__ float xs_o[ICH][XP + 3];
        __shared__ float wl[ICH][4][OT];
        for (int ic0 = 0; ic0 < I; ic0 += ICH) {
            __syncthreads();
            for (int e = tid; e < ICH * XP; e += 256) {
                int ii = e / XP, s = e - ii * XP;
                const float* xrow = xb + (size_t)(ic0 + ii) * Tin;
                int te = 2 * (t0 + s);
                int to = te - 1;
                xs_e[ii][s] = (te < Tin) ? xrow[te] : 0.f;
                xs_o[ii][s] = (to >= 0) ? xrow[to] : 0.f;
            }
            for (int e = tid; e < ICH * 4 * OT; e += 256) {
                int q = e >> 6;
                (&wl[0][0][0])[e] = wT[(size_t)(ic0 * 4 + q) * O + o0 + (e & 63)];
            }
            __syncthreads();
#pragma unroll
            for (int ii = 0; ii < ICH; ii++) {
                double re[5], ro[5];
#pragma unroll
                for (int m = 0; m < 5; m++) {
                    re[m] = (double)xs_e[ii][tx * 4 + m];
                    ro[m] = (double)xs_o[ii][tx * 4 + m];
                }
#pragma unroll
                for (int k = 0; k < 4; k++) {
                    double wv[4];
#pragma unroll
                    for (int c = 0; c < 4; c++) wv[c] = (double)wl[ii][k][ty * 4 + c];
                    const double* xr = (k & 1) ? re : ro;
                    const int offs = k >> 1;
#pragma unroll
                    for (int j = 0; j < 4; j++)
#pragma unroll
                        for (int c = 0; c < 4; c++) acc[j][c] = fma(xr[j + offs], wv[c], acc[j][c]);
                }
            }
        }
    }

    float* yb = y + (size_t)b * O * Tout;
#pragma unroll
    for (int c = 0; c < 4; c++) {
        int o = o0 + ty * 4 + c;
        double bv = (double)bias[o];
        double r0 = acc[0][c] + bv, r1 = acc[1][c] + bv, r2 = acc[2][c] + bv, r3 = acc[3][c] + bv;
        if (RELU) {
            r0 = r0 > 0.0 ? r0 : 0.0;
            r1 = r1 > 0.0 ? r1 : 0.0;
            r2 = r2 > 0.0 ? r2 : 0.0;
            r3 = r3 > 0.0 ? r3 : 0.0;
        }
        float4 v;
        v.x = (float)r0; v.y = (float)r1; v.z = (float)r2; v.w = (float)r3;
        *(float4*)&yb[(size_t)o * Tout + t0 + tx * 4] = v;
    }
}

// ---------------- decoder conv1d (pad=1), fp32 ----------------
template <int K, int STRIDE, bool RELU>
__global__ __launch_bounds__(256) void conv1d_kernel(const float* __restrict__ x,
                                                     const float* __restrict__ wT,
                                                     const float* __restrict__ bias,
                                                     float* __restrict__ y,
                                                     int I, int O, int Tin, int Tout) {
    const int b = blockIdx.z;
    const int o0 = blockIdx.y * OT;
    const int t0 = blockIdx.x * TT;
    const int tid = threadIdx.x;
    const int tx = tid & 15;
    const int ty = tid >> 4;
    constexpr int XW = (TT - 1) * STRIDE + K;
    __shared__ float xs[ICH][XW + 2];
    __shared__ float wl[ICH][K][OT];

    float acc[4][4];
#pragma unroll
    for (int j = 0; j < 4; j++)
#pragma unroll
        for (int c = 0; c < 4; c++) acc[j][c] = 0.f;

    const float* xb = x + (size_t)b * I * Tin;

    for (int ic0 = 0; ic0 < I; ic0 += ICH) {
        __syncthreads();
        for (int e = tid; e < ICH * XW; e += 256) {
            int ii = e / XW;
            int m = e - ii * XW;
            int tin = t0 * STRIDE - 1 + m;
            float v = 0.f;
            if (tin >= 0 && tin < Tin) v = xb[(size_t)(ic0 + ii) * Tin + tin];
            xs[ii][m] = v;
        }
        for (int e = tid; e < ICH * K * OT; e += 256) {
            int q = e >> 6;
            (&wl[0][0][0])[e] = wT[(size_t)(ic0 * K + q) * O + o0 + (e & 63)];
        }
        __syncthreads();
#pragma unroll
        for (int ii = 0; ii < ICH; ii++) {
            float xr[3 * STRIDE + K];
#pragma unroll
            for (int m = 0; m < 3 * STRIDE + K; m++)
                xr[m] = xs[ii][tx * 4 * STRIDE + m];
#pragma unroll
            for (int k = 0; k < K; k++) {
                float wv[4];
#pragma unroll
                for (int c = 0; c < 4; c++) wv[c] = wl[ii][k][ty * 4 + c];
#pragma unroll
                for (int j = 0; j < 4; j++) {
                    float xv = xr[j * STRIDE + k];
#pragma unroll
                    for (int c = 0; c < 4; c++) acc[j][c] = fmaf(xv, wv[c], acc[j][c]);
                }
            }
        }
    }
    float* yb = y + (size_t)b * O * Tout;
#pragma unroll
    for (int c = 0; c < 4; c++) {
        int o = o0 + ty * 4 + c;
        float bv = bias[o];
        float4 v;
        v.x = acc[0][c] + bv;
        v.y = acc[1][c] + bv;
        v.z = acc[2][c] + bv;
        v.w = acc[3][c] + bv;
        if (RELU) {
            v.x = fmaxf(v.x, 0.f); v.y = fmaxf(v.y, 0.f);
            v.z = fmaxf(v.z, 0.f); v.w = fmaxf(v.w, 0.f);
        }
        *(float4*)&yb[(size_t)o * Tout + t0 + tx * 4] = v;
    }
}

// ---------------- ConvTranspose1d (K=4, stride=2, pad=1), fp32 ----------------
template <bool RELU>
__global__ __launch_bounds__(256) void convT_kernel(const float* __restrict__ x,
                                                    const float* __restrict__ wT,
                                                    const float* __restrict__ bias,
                                                    float* __restrict__ y,
                                                    int I, int O, int Tin) {
    const int Tout = 2 * Tin;
    const int b = blockIdx.z;
    const int o0 = blockIdx.y * OT;
    const int t0 = blockIdx.x * TT;
    const int tid = threadIdx.x;
    const int tx = tid & 15, ty = tid >> 4;
    constexpr int XW = 34;
    __shared__ float xs[ICH][XW + 2];
    __shared__ float wl[ICH][4][OT];
    float acc[4][4];
#pragma unroll
    for (int j = 0; j < 4; j++)
#pragma unroll
        for (int c = 0; c < 4; c++) acc[j][c] = 0.f;
    const float* xb = x + (size_t)b * I * Tin;
    for (int ic0 = 0; ic0 < I; ic0 += ICH) {
        __syncthreads();
        for (int e = tid; e < ICH * XW; e += 256) {
            int ii = e / XW, m = e - ii * XW;
            int tin = t0 / 2 - 1 + m;
            xs[ii][m] = (tin >= 0 && tin < Tin) ? xb[(size_t)(ic0 + ii) * Tin + tin] : 0.f;
        }
        for (int e = tid; e < ICH * 4 * OT; e += 256) {
            int q = e >> 6, oo = e & 63;
            (&wl[0][0][0])[e] = wT[(size_t)(ic0 * 4 + q) * O + o0 + oo];
        }
        __syncthreads();
#pragma unroll
        for (int ii = 0; ii < ICH; ii++) {
            float xr[4];
#pragma unroll
            for (int m = 0; m < 4; m++) xr[m] = xs[ii][2 * tx + m];
            float w0[4], w1[4], w2[4], w3[4];
#pragma unroll
            for (int c = 0; c < 4; c++) {
                w0[c] = wl[ii][0][ty * 4 + c];
                w1[c] = wl[ii][1][ty * 4 + c];
                w2[c] = wl[ii][2][ty * 4 + c];
                w3[c] = wl[ii][3][ty * 4 + c];
            }
#pragma unroll
            for (int c = 0; c < 4; c++) {
                acc[0][c] = fmaf(xr[1], w1[c], fmaf(xr[0], w3[c], acc[0][c]));
                acc[1][c] = fmaf(xr[2], w0[c], fmaf(xr[1], w2[c], acc[1][c]));
                acc[2][c] = fmaf(xr[2], w1[c], fmaf(xr[1], w3[c], acc[2][c]));
                acc[3][c] = fmaf(xr[3], w0[c], fmaf(xr[2], w2[c], acc[3][c]));
            }
        }
    }
    float* yb = y + (size_t)b * O * Tout;
#pragma unroll
    for (int c = 0; c < 4; c++) {
        int o = o0 + ty * 4 + c;
        float bv = bias[o];
        float4 v;
        v.x = acc[0][c] + bv;
        v.y = acc[1][c] + bv;
        v.z = acc[2][c] + bv;
        v.w = acc[3][c] + bv;
        if (RELU) {
            v.x = fmaxf(v.x, 0.f); v.y = fmaxf(v.y, 0.f);
            v.z = fmaxf(v.z, 0.f); v.w = fmaxf(v.w, 0.f);
        }
        *(float4*)&yb[(size_t)o * Tout + t0 + tx * 4] = v;
    }
}

// ---------------- numpy-style pairwise fp32 sum of squares (n=512) ----------------
template <typename GET>
__device__ __forceinline__ float np_sum512_sq(GET get) {
    float p[4];
#pragma unroll
    for (int blk = 0; blk < 4; blk++) {
        int base = blk * 128;
        float r[8];
#pragma unroll
        for (int j = 0; j < 8; j++) { float v = get(base + j); r[j] = fmul(v, v); }
        for (int i = 8; i < 128; i += 8) {
#pragma unroll
            for (int j = 0; j < 8; j++) { float v = get(base + i + j); r[j] = fadd(r[j], fmul(v, v)); }
        }
        p[blk] = fadd(fadd(fadd(r[0], r[1]), fadd(r[2], r[3])),
                      fadd(fadd(r[4], r[5]), fadd(r[6], r[7])));
    }
    return fadd(fadd(p[0], p[1]), fadd(p[2], p[3]));
}

// zn32[n] = fp32 pairwise sum of z_row^2 ; z layout [B][D][Tq]
__global__ __launch_bounds__(256) void zn32_kernel(const float* __restrict__ z, float* __restrict__ zn32) {
    int n = blockIdx.x * 256 + threadIdx.x;  // 8192
    int b = n >> 7, tq = n & 127;
    const float* zb = z + ((size_t)b << 16) + tq;
    zn32[n] = np_sum512_sq([&](int d) { return zb[d << 7]; });
}

// cn32[j] = fp32 pairwise sum of cb_row^2
__global__ __launch_bounds__(256) void cn32_kernel(const float* __restrict__ cb, float* __restrict__ cn32) {
    int j = blockIdx.x * 256 + threadIdx.x;  // 512
    const float* cr = cb + ((size_t)j << 9);
    cn32[j] = np_sum512_sq([&](int d) { return cr[d]; });
}

// ---------------- VQ partial argmin over a quarter of the codebook ----------------
// Exact fp64 dots + exact fp32 d32-formula emulation; per-(n,j) value identical
// to the monolithic version. blockIdx.x = n-tile (64 rows), blockIdx.y = quarter
// (128 codes). Partial best (d32, idx) written to pval/pidx.
__global__ __launch_bounds__(256) void vq_partial_kernel(const float* __restrict__ z,
                                                         const float* __restrict__ cT,
                                                         const float* __restrict__ cn32,
                                                         const float* __restrict__ zn32,
                                                         float* __restrict__ pval,
                                                         int* __restrict__ pidx) {
    const int n0 = blockIdx.x * 64;
    const int q  = blockIdx.y;           // 0..3
    const int jbeg = q * 128;
    const int b = n0 >> 7;
    const int tq0 = n0 & 127;
    const int tid = threadIdx.x;
    const int tx = tid & 15, ty = tid >> 4;
    constexpr int DCH = 32;
    __shared__ double zs[DCH][65];
    __shared__ double cs[DCH][64];
    __shared__ float rv[64][16];
    __shared__ int ri[64][16];

    float b1[4];
    int i1[4];
    float zn[4];
#pragma unroll
    for (int a = 0; a < 4; a++) {
        b1[a] = 3.4e38f; i1[a] = 0;
        zn[a] = zn32[n0 + ty * 4 + a];
    }

    for (int j0 = jbeg; j0 < jbeg + 128; j0 += 64) {
        double acc[4][4];
#pragma unroll
        for (int a = 0; a < 4; a++)
#pragma unroll
            for (int c = 0; c < 4; c++) acc[a][c] = 0.0;
        for (int d0 = 0; d0 < 512; d0 += DCH) {
            __syncthreads();
            for (int e = tid; e < DCH * 64; e += 256) {
                int dd = e >> 6, nn = e & 63;
                zs[dd][nn] = (double)z[((size_t)b * 512 + d0 + dd) * 128 + tq0 + nn];
            }
            for (int e = tid; e < DCH * 64; e += 256) {
                int dd = e >> 6, jj = e & 63;
                cs[dd][jj] = (double)cT[(size_t)(d0 + dd) * 512 + j0 + jj];
            }
            __syncthreads();
#pragma unroll
            for (int dd = 0; dd < DCH; dd++) {
                double zv[4], cv[4];
#pragma unroll
                for (int a = 0; a < 4; a++) zv[a] = zs[dd][ty * 4 + a];
#pragma unroll
                for (int c = 0; c < 4; c++) cv[c] = cs[dd][tx * 4 + c];
#pragma unroll
                for (int a = 0; a < 4; a++)
#pragma unroll
                    for (int c = 0; c < 4; c++) acc[a][c] = fma(zv[a], cv[c], acc[a][c]);
            }
        }
#pragma unroll
        for (int c = 0; c < 4; c++) {
            int j = j0 + tx * 4 + c;
            float cnv = cn32[j];
#pragma unroll
            for (int a = 0; a < 4; a++) {
                float C32 = (float)acc[a][c];
                float t1  = fadd(zn[a], cnv);
                float d32 = fadd(t1, fmul(-2.f, C32));
                if (d32 < b1[a]) { b1[a] = d32; i1[a] = j; }
            }
        }
    }
    __syncthreads();
#pragma unroll
    for (int a = 0; a < 4; a++) {
        rv[ty * 4 + a][tx] = b1[a];
        ri[ty * 4 + a][tx] = i1[a];
    }
    __syncthreads();
    if (tid < 64) {
        float bv = rv[tid][0];
        int bi = ri[tid][0];
#pragma unroll
        for (int t = 1; t < 16; t++) {
            float v = rv[tid][t];
            int ji = ri[tid][t];
            if (v < bv || (v == bv && ji < bi)) { bv = v; bi = ji; }
        }
        pval[(size_t)q * 8192 + n0 + tid] = bv;
        pidx[(size_t)q * 8192 + n0 + tid] = bi;
    }
}

// ---------------- merge quarters (ascending q keeps lowest-index ties) ----------------
__global__ __launch_bounds__(256) void vq_merge_kernel(const float* __restrict__ pval,
                                                       const int* __restrict__ pidx,
                                                       int* __restrict__ idx_out,
                                                       float* __restrict__ idxf_out) {
    int n = blockIdx.x * 256 + threadIdx.x;  // 8192
    float bv = pval[n];
    int bi = pidx[n];
#pragma unroll
    for (int q = 1; q < 4; q++) {
        float v = pval[(size_t)q * 8192 + n];
        int i = pidx[(size_t)q * 8192 + n];
        if (v < bv) { bv = v; bi = i; }   // tie (v==bv): keep lower q -> lower index
    }
    idx_out[n] = bi;
    idxf_out[n] = (float)bi;
}

// ---------------- straight-through + commitment loss ----------------
__global__ __launch_bounds__(256) void zq_st_kernel(const float* __restrict__ z,
                                                    const float* __restrict__ cb,
                                                    const int* __restrict__ idx,
                                                    float* __restrict__ zq,
                                                    double* __restrict__ lossAcc) {
    const int total = 64 * 512 * 128;
    double part = 0.0;
    for (int e = blockIdx.x * 256 + threadIdx.x; e < total; e += gridDim.x * 256) {
        int tq = e & 127;
        int d = (e >> 7) & 511;
        int b = e >> 16;
        float zv = z[e];
        float cv = cb[(size_t)idx[(b << 7) + tq] * 512 + d];
        double diff = (double)zv - (double)cv;
        part = fma(diff, diff, part);
        zq[e] = zv + (cv - zv);
    }
    __shared__ double red[256];
    red[threadIdx.x] = part;
    __syncthreads();
    for (int s = 128; s; s >>= 1) {
        if (threadIdx.x < (unsigned)s) red[threadIdx.x] += red[threadIdx.x + s];
        __syncthreads();
    }
    if (threadIdx.x == 0) atomicAdd(lossAcc, red[0]);
}

__global__ void finalize_kernel(const double* __restrict__ lossAcc, float* __restrict__ out_loss) {
    *out_loss = (float)(0.25 * (*lossAcc) / (double)(64 * 512 * 128));
}

// ---------------- host ----------------
extern "C" void kernel_launch(void* const* d_in, const int* in_sizes, int n_in,
                              void* d_out, int out_size, void* d_ws, size_t ws_size,
                              hipStream_t stream) {
    const float* x    = (const float*)d_in[0];
    const float* ew1  = (const float*)d_in[1];  const float* eb1 = (const float*)d_in[2];
    const float* ew2  = (const float*)d_in[3];  const float* eb2 = (const float*)d_in[4];
    const float* ew3  = (const float*)d_in[5];  const float* eb3 = (const float*)d_in[6];
    const float* ew4  = (const float*)d_in[7];  const float* eb4 = (const float*)d_in[8];
    const float* ew5  = (const float*)d_in[9];  const float* eb5 = (const float*)d_in[10];
    const float* cb   = (const float*)d_in[11];
    const float* dw1  = (const float*)d_in[12]; const float* db1  = (const float*)d_in[13];
    const float* dwt2 = (const float*)d_in[14]; const float* dbt2 = (const float*)d_in[15];
    const float* dw3  = (const float*)d_in[16]; const float* db3  = (const float*)d_in[17];
    const float* dwt4 = (const float*)d_in[18]; const float* dbt4 = (const float*)d_in[19];
    const float* dw5  = (const float*)d_in[20]; const float* db5  = (const float*)d_in[21];

    float* out = (float*)d_out;
    float* ws = (float*)d_ws;

    const int B = 64, T = 512, F = 256, D = 512, Kcb = 512, Tq = 128;

    size_t off = 0;
    auto alloc = [&](size_t n) { size_t o = off; off += n; return o; };
    float* bufA = ws + alloc((size_t)B * 512 * 512);
    float* bufB = ws + alloc((size_t)B * 512 * 512);
    float* bufC = ws + alloc((size_t)B * 512 * 512);
    float* cT    = ws + alloc((size_t)D * Kcb);
    float* cn32  = ws + alloc(Kcb);
    float* zn32  = ws + alloc(B * Tq);
    float* pval  = ws + alloc(4 * 8192);
    int*   pidx  = (int*)(ws + alloc(4 * 8192));
    int*   idxb  = (int*)(ws + alloc(B * Tq));
    double* lossAcc = (double*)(ws + alloc(2));
    float* wtE1  = ws + alloc((size_t)256 * 3 * 256);
    float* wtE2  = ws + alloc((size_t)256 * 4 * 256);
    float* wtE3  = ws + alloc((size_t)256 * 3 * 512);
    float* wtE4  = ws + alloc((size_t)512 * 4 * 512);
    float* wtE5  = ws + alloc((size_t)512 * 3 * 512);
    float* wtD1  = ws + alloc((size_t)512 * 3 * 512);
    float* wtDT2 = ws + alloc((size_t)512 * 4 * 512);
    float* wtD3  = ws + alloc((size_t)512 * 3 * 256);
    float* wtDT4 = ws + alloc((size_t)256 * 4 * 256);
    float* wtD5  = ws + alloc((size_t)256 * 3 * 256);
    (void)ws_size; (void)in_sizes; (void)n_in; (void)out_size;

    hipMemsetAsync(lossAcc, 0, sizeof(double), stream);

    auto wtc = [&](const float* w, float* wT, int O, int I, int K) {
        int tot = O * I * K;
        wt_conv_kernel<<<(tot + 255) / 256, 256, 0, stream>>>(w, wT, O, I, K);
    };
    auto wtct = [&](const float* w, float* wT, int I, int O, int K) {
        int tot = O * I * K;
        wt_convT_kernel<<<(tot + 255) / 256, 256, 0, stream>>>(w, wT, I, O, K);
    };
    wtc(ew1, wtE1, 256, 256, 3);
    wtc(ew2, wtE2, 256, 256, 4);
    wtc(ew3, wtE3, 512, 256, 3);
    wtc(ew4, wtE4, 512, 512, 4);
    wtc(ew5, wtE5, 512, 512, 3);
    wtc(dw1, wtD1, 512, 512, 3);
    wtct(dwt2, wtDT2, 512, 512, 4);
    wtc(dw3, wtD3, 256, 512, 3);
    wtct(dwt4, wtDT4, 256, 256, 4);
    wtc(dw5, wtD5, 256, 256, 3);

    // codebook prep
    transpose_kernel<<<dim3(512 / 32, 512 / 32, 1), dim3(32, 8), 0, stream>>>(cb, cT, Kcb, D);
    cn32_kernel<<<2, 256, 0, stream>>>(cb, cn32);

    // x [B,T,F] -> bufA [B,F,T]
    transpose_kernel<<<dim3(F / 32, T / 32, B), dim3(32, 8), 0, stream>>>(x, bufA, T, F);

    // encoder (fp64 accumulation, fp32 LDS)
    conv1d_f64_kernel<3, 1, true ><<<dim3(512 / TT, 256 / OT, B), 256, 0, stream>>>(bufA, wtE1, eb1, bufB, 256, 256, 512, 512);
    conv1d_f64_kernel<4, 2, true ><<<dim3(256 / TT, 256 / OT, B), 256, 0, stream>>>(bufB, wtE2, eb2, bufC, 256, 256, 512, 256);
    conv1d_f64_kernel<3, 1, true ><<<dim3(256 / TT, 512 / OT, B), 256, 0, stream>>>(bufC, wtE3, eb3, bufA, 256, 512, 256, 256);
    conv1d_f64_kernel<4, 2, true ><<<dim3(128 / TT, 512 / OT, B), 256, 0, stream>>>(bufA, wtE4, eb4, bufB, 512, 512, 256, 128);
    conv1d_f64_kernel<3, 1, false><<<dim3(128 / TT, 512 / OT, B), 256, 0, stream>>>(bufB, wtE5, eb5, bufC, 512, 512, 128, 128);

    // VQ: fp32-formula-faithful argmin, j-split x4 + merge
    zn32_kernel<<<32, 256, 0, stream>>>(bufC, zn32);
    vq_partial_kernel<<<dim3(128, 4), 256, 0, stream>>>(bufC, cT, cn32, zn32, pval, pidx);
    vq_merge_kernel<<<32, 256, 0, stream>>>(pval, pidx, idxb, out + (size_t)8388608);
    zq_st_kernel<<<2048, 256, 0, stream>>>(bufC, cb, idxb, bufA, lossAcc);

    // decoder (fp32)
    conv1d_kernel<3, 1, true ><<<dim3(128 / TT, 512 / OT, B), 256, 0, stream>>>(bufA, wtD1, db1, bufB, 512, 512, 128, 128);
    convT_kernel<true><<<dim3(256 / TT, 512 / OT, B), 256, 0, stream>>>(bufB, wtDT2, dbt2, bufA, 512, 512, 128);
    conv1d_kernel<3, 1, true ><<<dim3(256 / TT, 256 / OT, B), 256, 0, stream>>>(bufA, wtD3, db3, bufB, 512, 256, 256, 256);
    convT_kernel<true><<<dim3(512 / TT, 256 / OT, B), 256, 0, stream>>>(bufB, wtDT4, dbt4, bufA, 256, 256, 256);
    conv1d_kernel<3, 1, false><<<dim3(512 / TT, 256 / OT, B), 256, 0, stream>>>(bufA, wtD5, db5, bufB, 256, 256, 512, 512);

    transpose_kernel<<<dim3(T / 32, F / 32, B), dim3(32, 8), 0, stream>>>(bufB, out, F, T);

    finalize_kernel<<<1, 1, 0, stream>>>(lossAcc, out + (size_t)8396800);
}